// Round 2
// 1023.098 us; speedup vs baseline: 1.0714x; 1.0714x over previous
//
#include <hip/hip_runtime.h>

typedef __attribute__((ext_vector_type(8))) unsigned short u16x8;
typedef __attribute__((ext_vector_type(8))) short s16x8;
typedef __attribute__((ext_vector_type(4))) float f32x4;

#define B_ROWS 4096
#define KDIM 20000
#define NP 112        // N=100 padded to 7 x 16
#define LDT 72        // LDS row stride (bf16 elems): 144B, 16B-aligned; (m+q)%8 class uniform -> b128 floor
#define NSPLIT 16     // split-K factor: 64 x 16 = 1024 blocks = 4/CU (LDS 33.75KB -> 4 fit)
#define EPS 1e-5f

__device__ __forceinline__ float bf2f(unsigned short h) {
  unsigned int u = ((unsigned int)h) << 16;
  return __builtin_bit_cast(float, u);
}
__device__ __forceinline__ unsigned short f2bf(float f) {
  unsigned int u = __builtin_bit_cast(unsigned int, f);
  u += 0x7FFFu + ((u >> 16) & 1u);   // RNE
  return (unsigned short)(u >> 16);
}
// scalar float load, dtype-flexible
__device__ __forceinline__ float ldf(const void* p, int i, int isf32) {
  return isf32 ? ((const float*)p)[i] : bf2f(((const unsigned short*)p)[i]);
}
// 8 contiguous float-ish elems -> bf16x8 (idx is 8-aligned)
__device__ __forceinline__ u16x8 load8f(const void* p, size_t idx, int isf32) {
  if (isf32) {
    const float4* q = (const float4*)((const float*)p + idx);
    float4 a = q[0], b = q[1];
    u16x8 r;
    r[0]=f2bf(a.x); r[1]=f2bf(a.y); r[2]=f2bf(a.z); r[3]=f2bf(a.w);
    r[4]=f2bf(b.x); r[5]=f2bf(b.y); r[6]=f2bf(b.z); r[7]=f2bf(b.w);
    return r;
  }
  return *(const u16x8*)((const unsigned short*)p + idx);
}
// 8 mask values, kind: 0=i32 1=i8/bool 2=f32 3=bf16 4=i64
__device__ __forceinline__ void load8m(const void* p, size_t idx, int kind, int* m) {
  if (kind == 0) {
    const int* q = (const int*)p + idx;
    int4 a = *(const int4*)q, b = *(const int4*)(q + 4);
    m[0]=a.x!=0; m[1]=a.y!=0; m[2]=a.z!=0; m[3]=a.w!=0;
    m[4]=b.x!=0; m[5]=b.y!=0; m[6]=b.z!=0; m[7]=b.w!=0;
  } else if (kind == 1) {
    uint2 v = *(const uint2*)((const unsigned char*)p + idx);
    #pragma unroll
    for (int j = 0; j < 4; j++) m[j]     = ((v.x >> (8*j)) & 0xFFu) != 0;
    #pragma unroll
    for (int j = 0; j < 4; j++) m[4 + j] = ((v.y >> (8*j)) & 0xFFu) != 0;
  } else if (kind == 2) {
    const float* q = (const float*)p + idx;
    float4 a = *(const float4*)q, b = *(const float4*)(q + 4);
    m[0]=a.x!=0.f; m[1]=a.y!=0.f; m[2]=a.z!=0.f; m[3]=a.w!=0.f;
    m[4]=b.x!=0.f; m[5]=b.y!=0.f; m[6]=b.z!=0.f; m[7]=b.w!=0.f;
  } else if (kind == 3) {
    u16x8 v = *(const u16x8*)((const unsigned short*)p + idx);
    #pragma unroll
    for (int j = 0; j < 8; j++) m[j] = v[j] != 0;
  } else { // i64: little-endian low word carries 0/1
    const int* q = (const int*)p;
    #pragma unroll
    for (int j = 0; j < 8; j++) m[j] = q[2 * (idx + j)] != 0;
  }
}

// ---------------------------------------------------------------------------
// Runtime dtype detection from bit patterns. enc_g1 is all-ones.
// flags[0] = float dtype is fp32; flags[1] = mask kind
// Wave-parallel: 64 lanes x 4 words (was 1 thread x 256 serial dependent
// loads = up to ~100us of exposed latency on the critical path).
// ---------------------------------------------------------------------------
__global__ void detect_kernel(const void* g1, const void* mk, int* flags) {
  const int l = threadIdx.x & 63;
  const unsigned int* m = (const unsigned int*)mk;
  int gt1 = 0, isf = 0, isbf = 0, oddNZ = 0, evenNZ = 0;
  #pragma unroll
  for (int j = 0; j < 4; j++) {
    int i = l + 64 * j;
    unsigned int v = m[i];
    if ((v & 0xFFFFu) == 0x3F80u) isbf = 1;
    if (v == 0x3F800000u) isf = 1;
    if (v > 1u) gt1 = 1;
    if (v != 0u) { if (i & 1) oddNZ = 1; else evenNZ = 1; }
  }
  int sawBF = __any(isbf);
  int sawF32 = __any(isf);
  int sawGt1 = __any(gt1);
  int sawOddNZ = __any(oddNZ);
  int sawEvenNZ = __any(evenNZ);
  if (threadIdx.x == 0) {
    unsigned int gw = *(const unsigned int*)g1;
    int isf32 = (gw == 0x3F800000u) ? 1 : 0;   // bf16 pair of 1.0 = 0x3F803F80
    int kind;
    if (sawBF) kind = 3;
    else if (sawF32) kind = 2;
    else if (sawGt1) kind = 1;
    else if (sawEvenNZ && !sawOddNZ) kind = 4; // i64: odd words all zero
    else kind = 0;
    flags[0] = isf32;
    flags[1] = kind;
  }
}

// ---------------------------------------------------------------------------
// GEMM1: a1_raw[path][r][n] = sum_k X_path[r][k] * W1[n][k]
// Fused corruption select; both paths share the W LDS tile.
// Split-K over blockIdx.y (16 splits), fp32 atomicAdd accumulation.
// grid 64x16 = 1024 blocks = 4 blocks/CU (LDS 33.75KB, VGPR capped <=128).
// ---------------------------------------------------------------------------
__global__ __launch_bounds__(256, 4) void gemm1_kernel(
    const void* __restrict__ x,
    const void* __restrict__ mk,
    const void* __restrict__ xr,
    const void* __restrict__ w1,
    float* __restrict__ outc, float* __restrict__ outx,
    const int* __restrict__ flags)
{
  __shared__ unsigned short lX[64 * LDT];
  __shared__ unsigned short lXc[64 * LDT];
  __shared__ unsigned short lW[NP * LDT];

  const int isf32 = flags[0];
  const int mkind = flags[1];
  const int t = threadIdx.x;
  const int bx = blockIdx.x;     // 64 row-blocks of 64 rows
  const int split = blockIdx.y;  // 16 K-splits
  const int l = t & 63;
  const int wv = t >> 6;

  f32x4 acc[7], accc[7];
  #pragma unroll
  for (int i = 0; i < 7; i++) {
    acc[i]  = (f32x4){0.f, 0.f, 0.f, 0.f};
    accc[i] = (f32x4){0.f, 0.f, 0.f, 0.f};
  }

  const int arow = wv * 16 + (l & 15);  // A-frag row (m = lane&15)
  const int qoff = (l >> 4) * 8;        // k-offset within MFMA step (quad*8)

  for (int stage = split; stage < 313; stage += NSPLIT) { // 313 = ceil(20000/64)
    const int k0 = stage * 64;
    const int kvalid = min(64, KDIM - k0);             // 64 or 32 (last stage)

    // ---- stage X and Xc (64 rows x 64 k) ----
    #pragma unroll
    for (int i = 0; i < 2; i++) {
      int v = t + 256 * i;          // 0..511
      int row = v >> 3;             // 0..63
      int k8 = (v & 7) * 8;         // 0..56
      u16x8 xv = {0,0,0,0,0,0,0,0};
      u16x8 cv = {0,0,0,0,0,0,0,0};
      if (k8 < kvalid) {
        size_t base = (size_t)(bx * 64 + row) * KDIM + k0 + k8;
        xv = load8f(x, base, isf32);
        u16x8 rv = load8f(xr, base, isf32);
        int m[8];
        load8m(mk, base, mkind, m);
        #pragma unroll
        for (int j = 0; j < 8; j++) cv[j] = m[j] ? rv[j] : xv[j];
      }
      *(u16x8*)&lX[row * LDT + k8]  = xv;
      *(u16x8*)&lXc[row * LDT + k8] = cv;
    }
    // ---- stage W (112 rows x 64 k; rows >= 100 zero-filled) ----
    #pragma unroll
    for (int i = 0; i < 4; i++) {
      int v = t + 256 * i;
      if (v < 896) {                 // 112 * 8
        int row = v >> 3;
        int k8 = (v & 7) * 8;
        u16x8 wvv = {0,0,0,0,0,0,0,0};
        if (row < 100 && k8 < kvalid)
          wvv = load8f(w1, (size_t)row * KDIM + k0 + k8, isf32);
        *(u16x8*)&lW[row * LDT + k8] = wvv;
      }
    }
    __syncthreads();

    const int nk = (kvalid > 32) ? 2 : 1;
    for (int ks = 0; ks < nk; ks++) {
      const int ko = ks * 32 + qoff;
      s16x8 af = *(const s16x8*)&lX[arow * LDT + ko];
      s16x8 cf = *(const s16x8*)&lXc[arow * LDT + ko];
      #pragma unroll
      for (int tn = 0; tn < 7; tn++) {
        s16x8 bfr = *(const s16x8*)&lW[(tn * 16 + (l & 15)) * LDT + ko];
        acc[tn]  = __builtin_amdgcn_mfma_f32_16x16x32_bf16(af, bfr, acc[tn], 0, 0, 0);
        accc[tn] = __builtin_amdgcn_mfma_f32_16x16x32_bf16(cf, bfr, accc[tn], 0, 0, 0);
      }
    }
    __syncthreads();
  }

  // epilogue: C/D layout col=lane&15, row=(lane>>4)*4+reg (m89/m91-verified)
  const int qr = (l >> 4) * 4;
  const int cn = l & 15;
  #pragma unroll
  for (int tn = 0; tn < 7; tn++) {
    #pragma unroll
    for (int j = 0; j < 4; j++) {
      int row = bx * 64 + wv * 16 + qr + j;
      int col = tn * 16 + cn;
      atomicAdd(&outc[(size_t)row * NP + col], acc[tn][j]);
      atomicAdd(&outx[(size_t)row * NP + col], accc[tn][j]);
    }
  }
}

// ---------------------------------------------------------------------------
// Column stats (biased var, torch BN training mode). Optional fused bias+relu.
// grid: (100 cols, 2 paths)
// ---------------------------------------------------------------------------
__global__ __launch_bounds__(256) void stats_kernel(
    const float* __restrict__ A, int ldin, long strideA,
    const void* __restrict__ bias, int doRelu,
    float* __restrict__ mu_out, float* __restrict__ rstd_out,
    const int* __restrict__ flags)
{
  const int isf32 = flags[0];
  const int n = blockIdx.x;
  const int path = blockIdx.y;
  const float* Ap = A + (size_t)path * strideA;
  const float b = bias ? ldf(bias, n, isf32) : 0.f;
  float s = 0.f, ss = 0.f;
  for (int r = threadIdx.x; r < B_ROWS; r += 256) {
    float v = Ap[(size_t)r * ldin + n];
    if (doRelu) v = fmaxf(v + b, 0.f);
    s += v; ss += v * v;
  }
  #pragma unroll
  for (int off = 32; off > 0; off >>= 1) {
    s  += __shfl_down(s, off, 64);
    ss += __shfl_down(ss, off, 64);
  }
  __shared__ float red[8];
  const int wv = threadIdx.x >> 6;
  if ((threadIdx.x & 63) == 0) { red[wv] = s; red[4 + wv] = ss; }
  __syncthreads();
  if (threadIdx.x == 0) {
    float st  = red[0] + red[1] + red[2] + red[3];
    float sst = red[4] + red[5] + red[6] + red[7];
    float mu  = st * (1.f / B_ROWS);
    float var = sst * (1.f / B_ROWS) - mu * mu;
    mu_out[path * 100 + n]   = mu;
    rstd_out[path * 100 + n] = rsqrtf(fmaxf(var, 0.f) + EPS);
  }
}

// ---------------------------------------------------------------------------
// Small layer: h = [PRE: relu(raw+preB)] -> BN(mu,rstd,g,be) -> [POSTRELU]
//              out = h @ W^T + bout; FINAL -> d_out in detected float dtype.
// grid: (128 row-blocks of 32, 2 paths)
// ---------------------------------------------------------------------------
template<bool PRE, bool POSTRELU, bool OUTRELU, bool FINAL>
__global__ __launch_bounds__(256) void layer_kernel(
    const float* __restrict__ A, int ldin, long strideA,
    const void* __restrict__ preB,
    const float* __restrict__ mu, const float* __restrict__ rstd,
    const void* __restrict__ g, const void* __restrict__ be,
    const void* __restrict__ W, const void* __restrict__ bout,
    void* __restrict__ Out, int ldout, long strideO,
    const int* __restrict__ flags)
{
  __shared__ float Wl[100 * 101];   // pad 101: conflict-free across m
  __shared__ float Hl[32 * 104];
  const int isf32 = flags[0];
  const int t = threadIdx.x;
  const int path = blockIdx.y;
  const int r0 = blockIdx.x * 32;
  const float* Ap = A + (size_t)path * strideA;

  for (int i = t; i < 10000; i += 256)
    Wl[(i / 100) * 101 + (i % 100)] = ldf(W, i, isf32);

  for (int i = t; i < 3200; i += 256) {
    int r = i / 100, k = i % 100;
    float v = Ap[(size_t)(r0 + r) * ldin + k];
    if (PRE) v = fmaxf(v + ldf(preB, k, isf32), 0.f);
    v = (v - mu[path * 100 + k]) * rstd[path * 100 + k] * ldf(g, k, isf32)
        + ldf(be, k, isf32);
    if (POSTRELU) v = fmaxf(v, 0.f);
    Hl[r * 104 + k] = v;
  }
  __syncthreads();

  for (int i = t; i < 3200; i += 256) {
    int r = i / 100, m = i % 100;
    float acc = ldf(bout, m, isf32);
    const float* hp = &Hl[r * 104];
    const float* wp = &Wl[m * 101];
    #pragma unroll 4
    for (int k = 0; k < 100; k++) acc = fmaf(hp[k], wp[k], acc);
    if (OUTRELU) acc = fmaxf(acc, 0.f);
    size_t oidx = (size_t)path * strideO + (size_t)(r0 + r) * ldout + m;
    if (FINAL) {
      if (isf32) ((float*)Out)[oidx] = acc;
      else       ((unsigned short*)Out)[oidx] = f2bf(acc);
    } else {
      ((float*)Out)[oidx] = acc;
    }
  }
}

// ---------------------------------------------------------------------------
extern "C" void kernel_launch(void* const* d_in, const int* in_sizes, int n_in,
                              void* d_out, int out_size, void* d_ws, size_t ws_size,
                              hipStream_t stream)
{
  const void* x    = d_in[0];
  const void* mkP  = d_in[1];
  const void* xr   = d_in[2];
  const void* w1   = d_in[3];
  const void* b1   = d_in[4];
  const void* g1   = d_in[5];
  const void* be1  = d_in[6];
  const void* w2   = d_in[7];
  const void* b2   = d_in[8];
  const void* g2   = d_in[9];
  const void* be2  = d_in[10];
  const void* hw1  = d_in[11];
  const void* hb1  = d_in[12];
  const void* hg1  = d_in[13];
  const void* hbe1 = d_in[14];
  const void* hw2  = d_in[15];
  const void* hb2  = d_in[16];

  float* ws  = (float*)d_ws;
  float* a1c = ws;                  // [4096][112] fp32 raw (clean)
  float* a1x = ws + 458752;         // [4096][112] fp32 raw (corrupted)
  float* a2  = ws + 917504;         // [2][4096][100]
  float* a3  = ws + 1736704;        // [2][4096][100]
  float* st  = ws + 2555904;        // stats: 1200 floats
  float *mu1 = st,       *rs1 = st + 200;
  float *mu2 = st + 400, *rs2 = st + 600;
  float *mu3 = st + 800, *rs3 = st + 1000;
  int* flags = (int*)(ws + 2557200);

  // zero split-K accumulators (ws is poisoned 0xAA by the harness)
  hipMemsetAsync(d_ws, 0, 917504 * sizeof(float), stream);

  detect_kernel<<<1, 64, 0, stream>>>(g1, mkP, flags);

  gemm1_kernel<<<dim3(64, NSPLIT), 256, 0, stream>>>(x, mkP, xr, w1, a1c, a1x, flags);

  // stats over relu(a1_raw + b1)
  stats_kernel<<<dim3(100, 2), 256, 0, stream>>>(a1c, NP, 458752, b1, 1, mu1, rs1, flags);

  // a2 = relu( BN1(relu(a1_raw+b1)) @ W2^T + b2 )
  layer_kernel<true, false, true, false><<<dim3(128, 2), 256, 0, stream>>>(
      a1c, NP, 458752, b1, mu1, rs1, g1, be1, w2, b2, a2, 100, 409600, flags);

  stats_kernel<<<dim3(100, 2), 256, 0, stream>>>(a2, 100, 409600, nullptr, 0, mu2, rs2, flags);

  // a3 = BN2(a2) @ head_w1^T + head_b1
  layer_kernel<false, false, false, false><<<dim3(128, 2), 256, 0, stream>>>(
      a2, 100, 409600, nullptr, mu2, rs2, g2, be2, hw1, hb1, a3, 100, 409600, flags);

  stats_kernel<<<dim3(100, 2), 256, 0, stream>>>(a3, 100, 409600, nullptr, 0, mu3, rs3, flags);

  // out = relu(BN_h1(a3)) @ head_w2^T + head_b2 -> d_out, clean then corrupted
  layer_kernel<false, true, false, true><<<dim3(128, 2), 256, 0, stream>>>(
      a3, 100, 409600, nullptr, mu3, rs3, hg1, hbe1, hw2, hb2, d_out, 100, 409600, flags);
}